// Round 2
// baseline (324.103 us; speedup 1.0000x reference)
//
#include <hip/hip_runtime.h>

constexpr int B      = 4;
constexpr int T      = 4096;
constexpr int C      = 64;      // input dim
constexpr int H      = 64;      // head dim
constexpr int TILE   = 32;      // rows per compute block
constexpr int HALO   = 2;       // window radius
constexpr int HR     = TILE + 2 * HALO;   // 36 halo rows
constexpr int LS     = 68;      // LDS row stride (floats): 16B-aligned, breaks pow2 banks
constexpr int NT     = 256;     // threads per block
constexpr int NTILES = T / TILE;          // 128
constexpr int CBLOCKS = B * NTILES;       // 512 compute blocks
constexpr int FBLOCKS = 2048;             // streaming zero-fill blocks
constexpr int GRID    = CBLOCKS + FBLOCKS; // 2560 = 5 * 512 exactly
constexpr int T4     = T / 4;             // 1024 float4 chunks per attn row
constexpr unsigned TOTAL4 = (unsigned)B * (unsigned)T * (unsigned)T4; // 16,777,216

// LDS 36928 B/block -> 4 blocks/CU (147.7 KB of 160 KB). launch_bounds(256,4)
// caps VGPRs at 128 so 16 waves/CU are actually resident.
__global__ __launch_bounds__(NT, 4)
void sparse_attn_fused(const float* __restrict__ x,
                       const float* __restrict__ Wq,
                       const float* __restrict__ Wk,
                       const float* __restrict__ Wv,
                       float* __restrict__ out)
{
    __shared__ float sX[HR][LS];      // x halo rows (36 x 64 used)
    __shared__ float sW[C][LS];       // A = Wq^T@Wk, later Wv^T
    __shared__ float sU[TILE][LS];    // U = X@A, later Y = sum_d p_d x_{i+d}
    __shared__ float sS[TILE][8];     // probs (5 used per row)

    const int tid = threadIdx.x;
    const unsigned bid = blockIdx.x;
    const size_t attnBase = (size_t)B * T * H;

    // ================= FILL ROLE (4 of every 5 blocks) =================
    // Interleaved with compute in dispatch order so zero-stores flow at full
    // BW from t=0. Skips exactly the band-intersecting float4 chunks, which
    // the compute role writes fully composed -> disjoint addresses, no
    // ordering dependency. (Logic identical to the verified R1 kernel.)
    if (bid % 5u != 0u) {
        const unsigned fid = bid - bid / 5u - 1u;          // 0..2047
        float4* __restrict__ attn4 = (float4*)(out + attnBase);
        const unsigned base   = fid * NT + tid;
        const unsigned stride = (unsigned)FBLOCKS * NT;    // 524288 -> 32 iters
        const float4 z = make_float4(0.f, 0.f, 0.f, 0.f);
        for (unsigned n = base; n < TOTAL4; n += stride) {
            const int c4 = (int)(n & (T4 - 1));
            const int i  = (int)((n >> 10) & (T - 1));
            const int j0 = c4 << 2;
            if (j0 > i + HALO || j0 + 3 < i - HALO) attn4[n] = z;
        }
        return;
    }

    // ================= COMPUTE ROLE =================
    const unsigned cid = bid / 5u;          // 0..511
    const int b    = (int)(cid / NTILES);
    const int tile = (int)(cid % NTILES);
    const int row0 = tile * TILE;
    const float* xb = x + (size_t)b * T * C;

    // ---- P0: stage x halo; compute A = Wq^T @ Wk directly into sW ----
    // score(i,j) = q_i.k_j = x_i A x_j^T with A[c][c'] = sum_h Wq[h][c] Wk[h][c'].
    for (int s = tid; s < HR * (C / 4); s += NT) {
        const int lr = s >> 4;
        const int c4 = (s & 15) << 2;
        const int gr = row0 + lr - HALO;
        float4 v = make_float4(0.f, 0.f, 0.f, 0.f);
        if (gr >= 0 && gr < T) v = *(const float4*)(xb + (size_t)gr * C + c4);
        *(float4*)&sX[lr][c4] = v;
    }
    {
        // thread owns A[c][cp0..cp0+15]; Wq/Wk are 16 KB, L1/L2-hot (all blocks
        // read the same lines). Redundant per block but ~1 us and removes two
        // full GEMM phases + two W stagings.
        const int c   = tid >> 2;
        const int cp0 = (tid & 3) << 4;
        float acc[16];
#pragma unroll
        for (int j = 0; j < 16; ++j) acc[j] = 0.f;
#pragma unroll 4
        for (int h = 0; h < C; ++h) {
            const float  wq = Wq[h * 64 + c];
            const float4 k0 = *(const float4*)&Wk[h * 64 + cp0];
            const float4 k1 = *(const float4*)&Wk[h * 64 + cp0 + 4];
            const float4 k2 = *(const float4*)&Wk[h * 64 + cp0 + 8];
            const float4 k3 = *(const float4*)&Wk[h * 64 + cp0 + 12];
            acc[0]  = fmaf(wq, k0.x, acc[0]);  acc[1]  = fmaf(wq, k0.y, acc[1]);
            acc[2]  = fmaf(wq, k0.z, acc[2]);  acc[3]  = fmaf(wq, k0.w, acc[3]);
            acc[4]  = fmaf(wq, k1.x, acc[4]);  acc[5]  = fmaf(wq, k1.y, acc[5]);
            acc[6]  = fmaf(wq, k1.z, acc[6]);  acc[7]  = fmaf(wq, k1.w, acc[7]);
            acc[8]  = fmaf(wq, k2.x, acc[8]);  acc[9]  = fmaf(wq, k2.y, acc[9]);
            acc[10] = fmaf(wq, k2.z, acc[10]); acc[11] = fmaf(wq, k2.w, acc[11]);
            acc[12] = fmaf(wq, k3.x, acc[12]); acc[13] = fmaf(wq, k3.y, acc[13]);
            acc[14] = fmaf(wq, k3.z, acc[14]); acc[15] = fmaf(wq, k3.w, acc[15]);
        }
#pragma unroll
        for (int j = 0; j < 4; ++j)
            *(float4*)&sW[c][cp0 + 4 * j] =
                make_float4(acc[4*j], acc[4*j+1], acc[4*j+2], acc[4*j+3]);
    }
    __syncthreads();

    // ---- P1: U = X[tile] @ A  (all 256 threads: 2 rows x 4 cols each) ----
    {
        const int r0 = tid >> 4;            // 0..15 (rows r0, r0+16)
        const int h0 = (tid & 15) << 2;     // 0..60
        float acc[2][4];
#pragma unroll
        for (int k = 0; k < 2; ++k)
#pragma unroll
            for (int j = 0; j < 4; ++j) acc[k][j] = 0.f;
        for (int c4 = 0; c4 < C; c4 += 4) {
            const float4 xa = *(const float4*)&sX[r0 + HALO][c4];
            const float4 xc = *(const float4*)&sX[r0 + 16 + HALO][c4];
#pragma unroll
            for (int cc = 0; cc < 4; ++cc) {
                const float4 wv = *(const float4*)&sW[c4 + cc][h0];
                const float xs0 = (&xa.x)[cc];
                const float xs1 = (&xc.x)[cc];
                acc[0][0] = fmaf(xs0, wv.x, acc[0][0]);
                acc[0][1] = fmaf(xs0, wv.y, acc[0][1]);
                acc[0][2] = fmaf(xs0, wv.z, acc[0][2]);
                acc[0][3] = fmaf(xs0, wv.w, acc[0][3]);
                acc[1][0] = fmaf(xs1, wv.x, acc[1][0]);
                acc[1][1] = fmaf(xs1, wv.y, acc[1][1]);
                acc[1][2] = fmaf(xs1, wv.z, acc[1][2]);
                acc[1][3] = fmaf(xs1, wv.w, acc[1][3]);
            }
        }
        *(float4*)&sU[r0][h0]      = make_float4(acc[0][0], acc[0][1], acc[0][2], acc[0][3]);
        *(float4*)&sU[r0 + 16][h0] = make_float4(acc[1][0], acc[1][1], acc[1][2], acc[1][3]);
    }
    __syncthreads();

    // ---- P2: scores+softmax+band-write (tid<32); Wv^T staging (tid>=64) ----
    if (tid < TILE) {
        const int i  = tid;
        const int ig = row0 + i;
        float sc[5];
        float m = -__builtin_inff();
#pragma unroll
        for (int d = 0; d < 5; ++d) {
            const int jg = ig - HALO + d;
            float v = -__builtin_inff();
            if (jg >= 0 && jg < T) {
                float a = 0.f;
#pragma unroll
                for (int c4 = 0; c4 < C; c4 += 4) {
                    const float4 u  = *(const float4*)&sU[i][c4];
                    const float4 xk = *(const float4*)&sX[i + d][c4];
                    a += u.x * xk.x + u.y * xk.y + u.z * xk.z + u.w * xk.w;
                }
                v = a * 0.125f + (d > 2 ? 1.0f : 0.0f);   // scale C^-0.5; triu(+1) j>i
            }
            sc[d] = v;
            m = fmaxf(m, v);
        }
        float p[5];
        float sum = 0.f;
#pragma unroll
        for (int d = 0; d < 5; ++d) { p[d] = expf(sc[d] - m); sum += p[d]; }
        const float inv = 1.f / sum;
#pragma unroll
        for (int d = 0; d < 5; ++d) sS[i][d] = p[d] * inv;   // exp(-inf)=0 -> 0

        // band-containing float4 chunks, fully composed (zeros + probs).
        float* rowp = out + attnBase + ((size_t)b * T + ig) * T;
        const int cLo = (ig - HALO > 0 ? ig - HALO : 0) >> 2;
        const int cHi = (ig + HALO < T - 1 ? ig + HALO : T - 1) >> 2;
        for (int cch = cLo; cch <= cHi; ++cch) {
            float vv[4];
#pragma unroll
            for (int q = 0; q < 4; ++q) {
                const int d = (cch << 2) + q - (ig - HALO);
                vv[q] = (d >= 0 && d < 5) ? sS[i][d] : 0.f;  // LDS runtime idx: fine
            }
            *(float4*)(rowp + (cch << 2)) = make_float4(vv[0], vv[1], vv[2], vv[3]);
        }
    }
    if (tid >= 64) {   // waves 1-3 stage Wv^T; wave0 stays on the score path
        for (int s = tid - 64; s < C * H; s += NT - 64)
            sW[s & 63][s >> 6] = Wv[s];
    }
    __syncthreads();

    // ---- P4: Y[i][c] = sum_d p_d * X[i+d][c]  (into sU; U is dead) ----
    {
        const int i  = tid >> 3;            // 0..31
        const int c0 = (tid & 7) << 3;      // 0..56, 8 floats per thread
        float y[8];
#pragma unroll
        for (int j = 0; j < 8; ++j) y[j] = 0.f;
#pragma unroll
        for (int d = 0; d < 5; ++d) {
            const float pd = sS[i][d];
            const float4 a = *(const float4*)&sX[i + d][c0];
            const float4 b2 = *(const float4*)&sX[i + d][c0 + 4];
            y[0] = fmaf(pd, a.x, y[0]);  y[1] = fmaf(pd, a.y, y[1]);
            y[2] = fmaf(pd, a.z, y[2]);  y[3] = fmaf(pd, a.w, y[3]);
            y[4] = fmaf(pd, b2.x, y[4]); y[5] = fmaf(pd, b2.y, y[5]);
            y[6] = fmaf(pd, b2.z, y[6]); y[7] = fmaf(pd, b2.w, y[7]);
        }
        *(float4*)&sU[i][c0]     = make_float4(y[0], y[1], y[2], y[3]);
        *(float4*)&sU[i][c0 + 4] = make_float4(y[4], y[5], y[6], y[7]);
    }
    __syncthreads();

    // ---- P5: OP = Y @ Wv^T, stored straight to global ----
    {
        const int r0 = tid >> 4;
        const int h0 = (tid & 15) << 2;
        float acc[2][4];
#pragma unroll
        for (int k = 0; k < 2; ++k)
#pragma unroll
            for (int j = 0; j < 4; ++j) acc[k][j] = 0.f;
        for (int c4 = 0; c4 < C; c4 += 4) {
            const float4 ya = *(const float4*)&sU[r0][c4];
            const float4 yc = *(const float4*)&sU[r0 + 16][c4];
#pragma unroll
            for (int cc = 0; cc < 4; ++cc) {
                const float4 wv = *(const float4*)&sW[c4 + cc][h0];
                const float ys0 = (&ya.x)[cc];
                const float ys1 = (&yc.x)[cc];
                acc[0][0] = fmaf(ys0, wv.x, acc[0][0]);
                acc[0][1] = fmaf(ys0, wv.y, acc[0][1]);
                acc[0][2] = fmaf(ys0, wv.z, acc[0][2]);
                acc[0][3] = fmaf(ys0, wv.w, acc[0][3]);
                acc[1][0] = fmaf(ys1, wv.x, acc[1][0]);
                acc[1][1] = fmaf(ys1, wv.y, acc[1][1]);
                acc[1][2] = fmaf(ys1, wv.z, acc[1][2]);
                acc[1][3] = fmaf(ys1, wv.w, acc[1][3]);
            }
        }
        float* o = out + ((size_t)b * T + row0) * H;
        *(float4*)&o[(size_t)r0 * H + h0] =
            make_float4(acc[0][0], acc[0][1], acc[0][2], acc[0][3]);
        *(float4*)&o[(size_t)(r0 + 16) * H + h0] =
            make_float4(acc[1][0], acc[1][1], acc[1][2], acc[1][3]);
    }
}

extern "C" void kernel_launch(void* const* d_in, const int* in_sizes, int n_in,
                              void* d_out, int out_size, void* d_ws, size_t ws_size,
                              hipStream_t stream) {
    (void)in_sizes; (void)n_in; (void)d_ws; (void)ws_size; (void)out_size;
    const float* x  = (const float*)d_in[0];
    const float* Wq = (const float*)d_in[1];
    const float* Wk = (const float*)d_in[2];
    const float* Wv = (const float*)d_in[3];
    float* out = (float*)d_out;
    sparse_attn_fused<<<dim3(GRID), dim3(NT), 0, stream>>>(x, Wq, Wk, Wv, out);
}

// Round 3
// 311.101 us; speedup vs baseline: 1.0418x; 1.0418x over previous
//
#include <hip/hip_runtime.h>

constexpr int B      = 4;
constexpr int T      = 4096;
constexpr int C      = 64;      // input dim
constexpr int H      = 64;      // head dim
constexpr int TILE   = 32;      // rows per compute block
constexpr int HALO   = 2;       // window radius
constexpr int HR     = TILE + 2 * HALO;   // 36 halo rows
constexpr int LS     = 68;      // LDS row stride (floats): 16B-aligned, breaks pow2 banks
constexpr int NT     = 256;     // threads per block
constexpr int NTILES = T / TILE;          // 128
constexpr int CBLOCKS = B * NTILES;       // 512 compute blocks

// Zero-fill of the attn region is done by hipMemsetAsync before this kernel
// (runtime fill hits 82% HBM peak; every hand-rolled fill we tried was worse:
// R0 inline 115us, R1 trailing blocks 135us, R2 interleaved 159us kernel time).
// This kernel only computes and overwrites the band chunks + op rows.
// LDS 36928 B/block; launch_bounds(256,4) keeps VGPRs <=128.
__global__ __launch_bounds__(NT, 4)
void sparse_attn_compute(const float* __restrict__ x,
                         const float* __restrict__ Wq,
                         const float* __restrict__ Wk,
                         const float* __restrict__ Wv,
                         float* __restrict__ out)
{
    __shared__ float sX[HR][LS];      // x halo rows (36 x 64 used)
    __shared__ float sW[C][LS];       // A = Wq^T@Wk, later Wv^T
    __shared__ float sU[TILE][LS];    // U = X@A, later Y = sum_d p_d x_{i+d}
    __shared__ float sS[TILE][8];     // probs (5 used per row)

    const int tid = threadIdx.x;
    const size_t attnBase = (size_t)B * T * H;

    const int b    = (int)(blockIdx.x / NTILES);
    const int tile = (int)(blockIdx.x % NTILES);
    const int row0 = tile * TILE;
    const float* xb = x + (size_t)b * T * C;

    // ---- P0: stage x halo; compute A = Wq^T @ Wk directly into sW ----
    // score(i,j) = q_i.k_j = x_i A x_j^T with A[c][c'] = sum_h Wq[h][c] Wk[h][c'].
    for (int s = tid; s < HR * (C / 4); s += NT) {
        const int lr = s >> 4;
        const int c4 = (s & 15) << 2;
        const int gr = row0 + lr - HALO;
        float4 v = make_float4(0.f, 0.f, 0.f, 0.f);
        if (gr >= 0 && gr < T) v = *(const float4*)(xb + (size_t)gr * C + c4);
        *(float4*)&sX[lr][c4] = v;
    }
    {
        // thread owns A[c][cp0..cp0+15]; Wq/Wk are 16 KB, L1/L2-hot (all blocks
        // read the same lines). Redundant per block but removes two full GEMM
        // phases + two W stagings vs the q/k formulation.
        const int c   = tid >> 2;
        const int cp0 = (tid & 3) << 4;
        float acc[16];
#pragma unroll
        for (int j = 0; j < 16; ++j) acc[j] = 0.f;
#pragma unroll 4
        for (int h = 0; h < C; ++h) {
            const float  wq = Wq[h * 64 + c];
            const float4 k0 = *(const float4*)&Wk[h * 64 + cp0];
            const float4 k1 = *(const float4*)&Wk[h * 64 + cp0 + 4];
            const float4 k2 = *(const float4*)&Wk[h * 64 + cp0 + 8];
            const float4 k3 = *(const float4*)&Wk[h * 64 + cp0 + 12];
            acc[0]  = fmaf(wq, k0.x, acc[0]);  acc[1]  = fmaf(wq, k0.y, acc[1]);
            acc[2]  = fmaf(wq, k0.z, acc[2]);  acc[3]  = fmaf(wq, k0.w, acc[3]);
            acc[4]  = fmaf(wq, k1.x, acc[4]);  acc[5]  = fmaf(wq, k1.y, acc[5]);
            acc[6]  = fmaf(wq, k1.z, acc[6]);  acc[7]  = fmaf(wq, k1.w, acc[7]);
            acc[8]  = fmaf(wq, k2.x, acc[8]);  acc[9]  = fmaf(wq, k2.y, acc[9]);
            acc[10] = fmaf(wq, k2.z, acc[10]); acc[11] = fmaf(wq, k2.w, acc[11]);
            acc[12] = fmaf(wq, k3.x, acc[12]); acc[13] = fmaf(wq, k3.y, acc[13]);
            acc[14] = fmaf(wq, k3.z, acc[14]); acc[15] = fmaf(wq, k3.w, acc[15]);
        }
#pragma unroll
        for (int j = 0; j < 4; ++j)
            *(float4*)&sW[c][cp0 + 4 * j] =
                make_float4(acc[4*j], acc[4*j+1], acc[4*j+2], acc[4*j+3]);
    }
    __syncthreads();

    // ---- P1: U = X[tile] @ A  (all 256 threads: 2 rows x 4 cols each) ----
    {
        const int r0 = tid >> 4;            // 0..15 (rows r0, r0+16)
        const int h0 = (tid & 15) << 2;     // 0..60
        float acc[2][4];
#pragma unroll
        for (int k = 0; k < 2; ++k)
#pragma unroll
            for (int j = 0; j < 4; ++j) acc[k][j] = 0.f;
        for (int c4 = 0; c4 < C; c4 += 4) {
            const float4 xa = *(const float4*)&sX[r0 + HALO][c4];
            const float4 xc = *(const float4*)&sX[r0 + 16 + HALO][c4];
#pragma unroll
            for (int cc = 0; cc < 4; ++cc) {
                const float4 wv = *(const float4*)&sW[c4 + cc][h0];
                const float xs0 = (&xa.x)[cc];
                const float xs1 = (&xc.x)[cc];
                acc[0][0] = fmaf(xs0, wv.x, acc[0][0]);
                acc[0][1] = fmaf(xs0, wv.y, acc[0][1]);
                acc[0][2] = fmaf(xs0, wv.z, acc[0][2]);
                acc[0][3] = fmaf(xs0, wv.w, acc[0][3]);
                acc[1][0] = fmaf(xs1, wv.x, acc[1][0]);
                acc[1][1] = fmaf(xs1, wv.y, acc[1][1]);
                acc[1][2] = fmaf(xs1, wv.z, acc[1][2]);
                acc[1][3] = fmaf(xs1, wv.w, acc[1][3]);
            }
        }
        *(float4*)&sU[r0][h0]      = make_float4(acc[0][0], acc[0][1], acc[0][2], acc[0][3]);
        *(float4*)&sU[r0 + 16][h0] = make_float4(acc[1][0], acc[1][1], acc[1][2], acc[1][3]);
    }
    __syncthreads();

    // ---- P2: scores+softmax+band-write (tid<32); Wv^T staging (tid>=64) ----
    if (tid < TILE) {
        const int i  = tid;
        const int ig = row0 + i;
        float sc[5];
        float m = -__builtin_inff();
#pragma unroll
        for (int d = 0; d < 5; ++d) {
            const int jg = ig - HALO + d;
            float v = -__builtin_inff();
            if (jg >= 0 && jg < T) {
                float a = 0.f;
#pragma unroll
                for (int c4 = 0; c4 < C; c4 += 4) {
                    const float4 u  = *(const float4*)&sU[i][c4];
                    const float4 xk = *(const float4*)&sX[i + d][c4];
                    a += u.x * xk.x + u.y * xk.y + u.z * xk.z + u.w * xk.w;
                }
                v = a * 0.125f + (d > 2 ? 1.0f : 0.0f);   // scale C^-0.5; triu(+1) j>i
            }
            sc[d] = v;
            m = fmaxf(m, v);
        }
        float p[5];
        float sum = 0.f;
#pragma unroll
        for (int d = 0; d < 5; ++d) { p[d] = expf(sc[d] - m); sum += p[d]; }
        const float inv = 1.f / sum;
#pragma unroll
        for (int d = 0; d < 5; ++d) sS[i][d] = p[d] * inv;   // exp(-inf)=0 -> 0

        // band-containing float4 chunks, fully composed (zeros + probs).
        // Stream-ordered AFTER the hipMemsetAsync, so overwriting is safe.
        float* rowp = out + attnBase + ((size_t)b * T + ig) * T;
        const int cLo = (ig - HALO > 0 ? ig - HALO : 0) >> 2;
        const int cHi = (ig + HALO < T - 1 ? ig + HALO : T - 1) >> 2;
        for (int cch = cLo; cch <= cHi; ++cch) {
            float vv[4];
#pragma unroll
            for (int q = 0; q < 4; ++q) {
                const int d = (cch << 2) + q - (ig - HALO);
                vv[q] = (d >= 0 && d < 5) ? sS[i][d] : 0.f;  // LDS runtime idx: fine
            }
            *(float4*)(rowp + (cch << 2)) = make_float4(vv[0], vv[1], vv[2], vv[3]);
        }
    }
    if (tid >= 64) {   // waves 1-3 stage Wv^T; wave0 stays on the score path
        for (int s = tid - 64; s < C * H; s += NT - 64)
            sW[s & 63][s >> 6] = Wv[s];
    }
    __syncthreads();

    // ---- P3: Y[i][c] = sum_d p_d * X[i+d][c]  (into sU; U is dead) ----
    {
        const int i  = tid >> 3;            // 0..31
        const int c0 = (tid & 7) << 3;      // 0..56, 8 floats per thread
        float y[8];
#pragma unroll
        for (int j = 0; j < 8; ++j) y[j] = 0.f;
#pragma unroll
        for (int d = 0; d < 5; ++d) {
            const float pd = sS[i][d];
            const float4 a  = *(const float4*)&sX[i + d][c0];
            const float4 b2 = *(const float4*)&sX[i + d][c0 + 4];
            y[0] = fmaf(pd, a.x, y[0]);  y[1] = fmaf(pd, a.y, y[1]);
            y[2] = fmaf(pd, a.z, y[2]);  y[3] = fmaf(pd, a.w, y[3]);
            y[4] = fmaf(pd, b2.x, y[4]); y[5] = fmaf(pd, b2.y, y[5]);
            y[6] = fmaf(pd, b2.z, y[6]); y[7] = fmaf(pd, b2.w, y[7]);
        }
        *(float4*)&sU[i][c0]     = make_float4(y[0], y[1], y[2], y[3]);
        *(float4*)&sU[i][c0 + 4] = make_float4(y[4], y[5], y[6], y[7]);
    }
    __syncthreads();

    // ---- P4: OP = Y @ Wv^T, stored straight to global ----
    {
        const int r0 = tid >> 4;
        const int h0 = (tid & 15) << 2;
        float acc[2][4];
#pragma unroll
        for (int k = 0; k < 2; ++k)
#pragma unroll
            for (int j = 0; j < 4; ++j) acc[k][j] = 0.f;
        for (int c4 = 0; c4 < C; c4 += 4) {
            const float4 ya = *(const float4*)&sU[r0][c4];
            const float4 yc = *(const float4*)&sU[r0 + 16][c4];
#pragma unroll
            for (int cc = 0; cc < 4; ++cc) {
                const float4 wv = *(const float4*)&sW[c4 + cc][h0];
                const float ys0 = (&ya.x)[cc];
                const float ys1 = (&yc.x)[cc];
                acc[0][0] = fmaf(ys0, wv.x, acc[0][0]);
                acc[0][1] = fmaf(ys0, wv.y, acc[0][1]);
                acc[0][2] = fmaf(ys0, wv.z, acc[0][2]);
                acc[0][3] = fmaf(ys0, wv.w, acc[0][3]);
                acc[1][0] = fmaf(ys1, wv.x, acc[1][0]);
                acc[1][1] = fmaf(ys1, wv.y, acc[1][1]);
                acc[1][2] = fmaf(ys1, wv.z, acc[1][2]);
                acc[1][3] = fmaf(ys1, wv.w, acc[1][3]);
            }
        }
        float* o = out + ((size_t)b * T + row0) * H;
        *(float4*)&o[(size_t)r0 * H + h0] =
            make_float4(acc[0][0], acc[0][1], acc[0][2], acc[0][3]);
        *(float4*)&o[(size_t)(r0 + 16) * H + h0] =
            make_float4(acc[1][0], acc[1][1], acc[1][2], acc[1][3]);
    }
}

extern "C" void kernel_launch(void* const* d_in, const int* in_sizes, int n_in,
                              void* d_out, int out_size, void* d_ws, size_t ws_size,
                              hipStream_t stream) {
    (void)in_sizes; (void)n_in; (void)d_ws; (void)ws_size; (void)out_size;
    const float* x  = (const float*)d_in[0];
    const float* Wq = (const float*)d_in[1];
    const float* Wk = (const float*)d_in[2];
    const float* Wv = (const float*)d_in[3];
    float* out = (float*)d_out;

    // Zero the attn region with the runtime's fill kernel (measured 6.3-6.6 TB/s
    // = 82% HBM peak in this harness; our hand-rolled fills never beat 2 TB/s).
    // hipMemsetAsync is stream-ordered and graph-capture legal (memset node).
    float* attn = out + (size_t)B * T * H;
    (void)hipMemsetAsync((void*)attn, 0, (size_t)B * T * T * sizeof(float), stream);

    // Compute kernel overwrites the band chunks + writes op rows.
    sparse_attn_compute<<<dim3(CBLOCKS), dim3(NT), 0, stream>>>(x, Wq, Wk, Wv, out);
}

// Round 4
// 295.137 us; speedup vs baseline: 1.0981x; 1.0541x over previous
//
#include <hip/hip_runtime.h>

constexpr int B      = 4;
constexpr int T      = 4096;
constexpr int C      = 64;      // input dim
constexpr int H      = 64;      // head dim
constexpr int TILE   = 32;      // rows per compute block
constexpr int HALO   = 2;       // window radius
constexpr int HR     = TILE + 2 * HALO;   // 36 halo rows
constexpr int LS     = 68;      // LDS row stride (floats): 16B-aligned, breaks pow2 banks
constexpr int NT     = 256;     // threads per block
constexpr int NTILES = T / TILE;          // 128
constexpr int CBLOCKS = B * NTILES;       // 512 blocks (2/CU)
constexpr int T4     = T / 4;             // 1024 float4 chunks per attn row

// One kernel, 512 blocks. Compute phases first (~20us), then a branchless
// VALU-minimal zero-stream of the block's own 32x4096 attn rows (512 KB),
// one barrier (vmcnt drain == store BW time), then composed band-chunk
// overwrites from LDS probs. Fill history: hand fills with band-skip math
// ran ~2.5-3 TB/s (issue-bound: ~6 VALU per 16B store); memset node ~2.3;
// harness's bare fill sustains 6.3 -> strip the fill loop to ~1 VALU/store.
__global__ __launch_bounds__(NT, 2)
void sparse_attn_fused(const float* __restrict__ x,
                       const float* __restrict__ Wq,
                       const float* __restrict__ Wk,
                       const float* __restrict__ Wv,
                       float* __restrict__ out)
{
    __shared__ float sX[HR][LS];      // x halo rows (36 x 64 used)
    __shared__ float sW[C][LS];       // A = Wq^T@Wk, later Wv^T
    __shared__ float sU[TILE][LS];    // U = X@A, later Y = sum_d p_d x_{i+d}
    __shared__ float sS[TILE][8];     // probs (5 used per row)

    const int tid = threadIdx.x;
    const size_t attnBase = (size_t)B * T * H;

    const int b    = (int)(blockIdx.x / NTILES);
    const int tile = (int)(blockIdx.x % NTILES);
    const int row0 = tile * TILE;
    const float* xb = x + (size_t)b * T * C;

    // ---- P0: stage x halo; compute A = Wq^T @ Wk directly into sW ----
    // score(i,j) = q_i.k_j = x_i A x_j^T with A[c][c'] = sum_h Wq[h][c] Wk[h][c'].
    for (int s = tid; s < HR * (C / 4); s += NT) {
        const int lr = s >> 4;
        const int c4 = (s & 15) << 2;
        const int gr = row0 + lr - HALO;
        float4 v = make_float4(0.f, 0.f, 0.f, 0.f);
        if (gr >= 0 && gr < T) v = *(const float4*)(xb + (size_t)gr * C + c4);
        *(float4*)&sX[lr][c4] = v;
    }
    {
        // thread owns A[c][cp0..cp0+15]; Wq/Wk are 16 KB, L1/L2-hot.
        const int c   = tid >> 2;
        const int cp0 = (tid & 3) << 4;
        float acc[16];
#pragma unroll
        for (int j = 0; j < 16; ++j) acc[j] = 0.f;
#pragma unroll 4
        for (int h = 0; h < C; ++h) {
            const float  wq = Wq[h * 64 + c];
            const float4 k0 = *(const float4*)&Wk[h * 64 + cp0];
            const float4 k1 = *(const float4*)&Wk[h * 64 + cp0 + 4];
            const float4 k2 = *(const float4*)&Wk[h * 64 + cp0 + 8];
            const float4 k3 = *(const float4*)&Wk[h * 64 + cp0 + 12];
            acc[0]  = fmaf(wq, k0.x, acc[0]);  acc[1]  = fmaf(wq, k0.y, acc[1]);
            acc[2]  = fmaf(wq, k0.z, acc[2]);  acc[3]  = fmaf(wq, k0.w, acc[3]);
            acc[4]  = fmaf(wq, k1.x, acc[4]);  acc[5]  = fmaf(wq, k1.y, acc[5]);
            acc[6]  = fmaf(wq, k1.z, acc[6]);  acc[7]  = fmaf(wq, k1.w, acc[7]);
            acc[8]  = fmaf(wq, k2.x, acc[8]);  acc[9]  = fmaf(wq, k2.y, acc[9]);
            acc[10] = fmaf(wq, k2.z, acc[10]); acc[11] = fmaf(wq, k2.w, acc[11]);
            acc[12] = fmaf(wq, k3.x, acc[12]); acc[13] = fmaf(wq, k3.y, acc[13]);
            acc[14] = fmaf(wq, k3.z, acc[14]); acc[15] = fmaf(wq, k3.w, acc[15]);
        }
#pragma unroll
        for (int j = 0; j < 4; ++j)
            *(float4*)&sW[c][cp0 + 4 * j] =
                make_float4(acc[4*j], acc[4*j+1], acc[4*j+2], acc[4*j+3]);
    }
    __syncthreads();

    // ---- P1: U = X[tile] @ A  (all 256 threads: 2 rows x 4 cols each) ----
    {
        const int r0 = tid >> 4;            // 0..15 (rows r0, r0+16)
        const int h0 = (tid & 15) << 2;     // 0..60
        float acc[2][4];
#pragma unroll
        for (int k = 0; k < 2; ++k)
#pragma unroll
            for (int j = 0; j < 4; ++j) acc[k][j] = 0.f;
        for (int c4 = 0; c4 < C; c4 += 4) {
            const float4 xa = *(const float4*)&sX[r0 + HALO][c4];
            const float4 xc = *(const float4*)&sX[r0 + 16 + HALO][c4];
#pragma unroll
            for (int cc = 0; cc < 4; ++cc) {
                const float4 wv = *(const float4*)&sW[c4 + cc][h0];
                const float xs0 = (&xa.x)[cc];
                const float xs1 = (&xc.x)[cc];
                acc[0][0] = fmaf(xs0, wv.x, acc[0][0]);
                acc[0][1] = fmaf(xs0, wv.y, acc[0][1]);
                acc[0][2] = fmaf(xs0, wv.z, acc[0][2]);
                acc[0][3] = fmaf(xs0, wv.w, acc[0][3]);
                acc[1][0] = fmaf(xs1, wv.x, acc[1][0]);
                acc[1][1] = fmaf(xs1, wv.y, acc[1][1]);
                acc[1][2] = fmaf(xs1, wv.z, acc[1][2]);
                acc[1][3] = fmaf(xs1, wv.w, acc[1][3]);
            }
        }
        *(float4*)&sU[r0][h0]      = make_float4(acc[0][0], acc[0][1], acc[0][2], acc[0][3]);
        *(float4*)&sU[r0 + 16][h0] = make_float4(acc[1][0], acc[1][1], acc[1][2], acc[1][3]);
    }
    __syncthreads();

    // ---- P2: scores + softmax -> probs in sS (tid<32); Wv^T staging (tid>=64) ----
    if (tid < TILE) {
        const int i  = tid;
        const int ig = row0 + i;
        float sc[5];
        float m = -__builtin_inff();
#pragma unroll
        for (int d = 0; d < 5; ++d) {
            const int jg = ig - HALO + d;
            float v = -__builtin_inff();
            if (jg >= 0 && jg < T) {
                float a = 0.f;
#pragma unroll
                for (int c4 = 0; c4 < C; c4 += 4) {
                    const float4 u  = *(const float4*)&sU[i][c4];
                    const float4 xk = *(const float4*)&sX[i + d][c4];
                    a += u.x * xk.x + u.y * xk.y + u.z * xk.z + u.w * xk.w;
                }
                v = a * 0.125f + (d > 2 ? 1.0f : 0.0f);   // scale C^-0.5; triu(+1) j>i
            }
            sc[d] = v;
            m = fmaxf(m, v);
        }
        float p[5];
        float sum = 0.f;
#pragma unroll
        for (int d = 0; d < 5; ++d) { p[d] = expf(sc[d] - m); sum += p[d]; }
        const float inv = 1.f / sum;
#pragma unroll
        for (int d = 0; d < 5; ++d) sS[i][d] = p[d] * inv;   // exp(-inf)=0 -> 0
    }
    if (tid >= 64) {   // waves 1-3 stage Wv^T; wave0 stays on the score path
        for (int s = tid - 64; s < C * H; s += NT - 64)
            sW[s & 63][s >> 6] = Wv[s];
    }
    __syncthreads();

    // ---- P3: Y[i][c] = sum_d p_d * X[i+d][c]  (into sU; U is dead) ----
    {
        const int i  = tid >> 3;            // 0..31
        const int c0 = (tid & 7) << 3;      // 0..56, 8 floats per thread
        float y[8];
#pragma unroll
        for (int j = 0; j < 8; ++j) y[j] = 0.f;
#pragma unroll
        for (int d = 0; d < 5; ++d) {
            const float pd = sS[i][d];
            const float4 a  = *(const float4*)&sX[i + d][c0];
            const float4 b2 = *(const float4*)&sX[i + d][c0 + 4];
            y[0] = fmaf(pd, a.x, y[0]);  y[1] = fmaf(pd, a.y, y[1]);
            y[2] = fmaf(pd, a.z, y[2]);  y[3] = fmaf(pd, a.w, y[3]);
            y[4] = fmaf(pd, b2.x, y[4]); y[5] = fmaf(pd, b2.y, y[5]);
            y[6] = fmaf(pd, b2.z, y[6]); y[7] = fmaf(pd, b2.w, y[7]);
        }
        *(float4*)&sU[i][c0]     = make_float4(y[0], y[1], y[2], y[3]);
        *(float4*)&sU[i][c0 + 4] = make_float4(y[4], y[5], y[6], y[7]);
    }
    __syncthreads();

    // ---- P4: OP = Y @ Wv^T, stored straight to global ----
    {
        const int r0 = tid >> 4;
        const int h0 = (tid & 15) << 2;
        float acc[2][4];
#pragma unroll
        for (int k = 0; k < 2; ++k)
#pragma unroll
            for (int j = 0; j < 4; ++j) acc[k][j] = 0.f;
        for (int c4 = 0; c4 < C; c4 += 4) {
            const float4 ya = *(const float4*)&sU[r0][c4];
            const float4 yc = *(const float4*)&sU[r0 + 16][c4];
#pragma unroll
            for (int cc = 0; cc < 4; ++cc) {
                const float4 wv = *(const float4*)&sW[c4 + cc][h0];
                const float ys0 = (&ya.x)[cc];
                const float ys1 = (&yc.x)[cc];
                acc[0][0] = fmaf(ys0, wv.x, acc[0][0]);
                acc[0][1] = fmaf(ys0, wv.y, acc[0][1]);
                acc[0][2] = fmaf(ys0, wv.z, acc[0][2]);
                acc[0][3] = fmaf(ys0, wv.w, acc[0][3]);
                acc[1][0] = fmaf(ys1, wv.x, acc[1][0]);
                acc[1][1] = fmaf(ys1, wv.y, acc[1][1]);
                acc[1][2] = fmaf(ys1, wv.z, acc[1][2]);
                acc[1][3] = fmaf(ys1, wv.w, acc[1][3]);
            }
        }
        float* o = out + ((size_t)b * T + row0) * H;
        *(float4*)&o[(size_t)r0 * H + h0] =
            make_float4(acc[0][0], acc[0][1], acc[0][2], acc[0][3]);
        *(float4*)&o[(size_t)(r0 + 16) * H + h0] =
            make_float4(acc[1][0], acc[1][1], acc[1][2], acc[1][3]);
    }

    // ---- P5: branchless zero-stream of this block's 32x4096 attn rows ----
    // 128 float4 stores/thread, consecutive lanes -> consecutive 16B (1KB/wave
    // instr), constant 4KB pointer stride -> ~1 VALU per store. No band logic.
    {
        float4* __restrict__ p =
            (float4*)(out + attnBase) + ((size_t)b * T + row0) * T4 + tid;
        const float4 z = make_float4(0.f, 0.f, 0.f, 0.f);
#pragma unroll 8
        for (int k = 0; k < TILE * T4 / NT; ++k)   // 128
            p[(size_t)k * NT] = z;
    }
    __syncthreads();   // drain zero stores (this IS the store-BW time)

    // ---- P6: overwrite band-containing chunks, fully composed ----
    if (tid < TILE) {
        const int i  = tid;
        const int ig = row0 + i;
        float* rowp = out + attnBase + ((size_t)b * T + ig) * T;
        const int cLo = (ig - HALO > 0 ? ig - HALO : 0) >> 2;
        const int cHi = (ig + HALO < T - 1 ? ig + HALO : T - 1) >> 2;
        for (int cch = cLo; cch <= cHi; ++cch) {
            float vv[4];
#pragma unroll
            for (int q = 0; q < 4; ++q) {
                const int d = (cch << 2) + q - (ig - HALO);
                vv[q] = (d >= 0 && d < 5) ? sS[i][d] : 0.f;  // LDS runtime idx: fine
            }
            *(float4*)(rowp + (cch << 2)) = make_float4(vv[0], vv[1], vv[2], vv[3]);
        }
    }
}

extern "C" void kernel_launch(void* const* d_in, const int* in_sizes, int n_in,
                              void* d_out, int out_size, void* d_ws, size_t ws_size,
                              hipStream_t stream) {
    (void)in_sizes; (void)n_in; (void)d_ws; (void)ws_size; (void)out_size;
    const float* x  = (const float*)d_in[0];
    const float* Wq = (const float*)d_in[1];
    const float* Wk = (const float*)d_in[2];
    const float* Wv = (const float*)d_in[3];
    float* out = (float*)d_out;
    sparse_attn_fused<<<dim3(CBLOCKS), dim3(NT), 0, stream>>>(x, Wq, Wk, Wv, out);
}